// Round 3
// baseline (171.483 us; speedup 1.0000x reference)
//
#include <hip/hip_runtime.h>
#include <math.h>

#define D 3072
#define BATCH 512
#define NCLS 100

// ---------------------------------------------------------------------------
// K1: column sums over first index:  A[d] = sum_i a[i*D+d], B[d] = sum_i b[..]
// a,b are [D,D] fp32 row-major (KF=1). Grid: (96 row-chunks of 32, 3 col
// groups of 1024). Each thread owns 4 consecutive columns (float4), fully
// coalesced 1KB/wave loads, then 8 atomicAdds into ws (96 contenders/addr).
// ---------------------------------------------------------------------------
__global__ __launch_bounds__(256) void colsum_kernel(const float* __restrict__ a,
                                                     const float* __restrict__ b,
                                                     float* __restrict__ ws) {
    const int rc  = blockIdx.x;                    // 0..95
    const int cg  = blockIdx.y;                    // 0..2
    const int col = cg * 1024 + threadIdx.x * 4;   // 0..3068
    const int row0 = rc * 32;

    float4 sa = make_float4(0.f, 0.f, 0.f, 0.f);
    float4 sb = make_float4(0.f, 0.f, 0.f, 0.f);
    for (int r = 0; r < 32; ++r) {
        const int i = row0 + r;
        const float4 va = *(const float4*)(a + i * D + col);
        const float4 vb = *(const float4*)(b + i * D + col);
        sa.x += va.x; sa.y += va.y; sa.z += va.z; sa.w += va.w;
        sb.x += vb.x; sb.y += vb.y; sb.z += vb.z; sb.w += vb.w;
    }
    atomicAdd(&ws[col + 0], sa.x);
    atomicAdd(&ws[col + 1], sa.y);
    atomicAdd(&ws[col + 2], sa.z);
    atomicAdd(&ws[col + 3], sa.w);
    atomicAdd(&ws[D + col + 0], sb.x);
    atomicAdd(&ws[D + col + 1], sb.y);
    atomicAdd(&ws[D + col + 2], sb.z);
    atomicAdd(&ws[D + col + 3], sb.w);
}

// ---------------------------------------------------------------------------
// K2: fused Z + GEMM, split-K accumulated straight into d_out via atomics.
//   Z[b,d] = part1 + cos(x[b,d])*A[d] + sin(x[b,d])*B[d]   (on the fly)
//   out[b,c] += sum_{d in chunk j} Z[b,d] * fc_w[c,d]   (+ fcb[c] when j==0)
// Grid: (16 b-tiles of 32) x (32 k-chunks of 96). Block 256 threads.
// Per-thread register tile: 4b x 4c. Per k: 1x ds_read_b128 (W) + 4 broadcast
// b32 (Z) + 16 FMA -> VALU-bound. d_out must be zeroed before launch.
// ws usage: only ws[0:2D) (A,B colsums) -> 24 KB total scratch.
// ---------------------------------------------------------------------------
__global__ __launch_bounds__(256) void fused_gemm_kernel(
        const float* __restrict__ x,
        const float* __restrict__ w5,
        const float* __restrict__ n5,
        const float* __restrict__ fcw,
        const float* __restrict__ fcb,
        const float* __restrict__ ws,     // A = ws[0:D], B = ws[D:2D]
        float* __restrict__ out) {        // [512][100], pre-zeroed
    __shared__ __align__(16) float Zl[32 * 36];    // [b_local][k], stride 36
    __shared__ __align__(16) float Wl[32 * 132];   // [k][c], stride 132

    const int t  = threadIdx.x;
    const int bt = blockIdx.x;   // 0..15
    const int j  = blockIdx.y;   // 0..31
    const float* __restrict__ A = ws;
    const float* __restrict__ B = ws + D;

    float part1 = 0.f;
    #pragma unroll
    for (int i = 0; i < 4; ++i)
        part1 += w5[i + 1] * n5[i + 1] + w5[i] * n5[i];

    const int c0 = (t & 31) * 4;    // 0..124 (c0 >= 100 -> compute-only lanes)
    const int b0 = (t >> 5) * 4;    // 0..28
    const int kl = t & 31;          // staging d-lane
    const int tg = t >> 5;          // staging b-group, 0..7
    const int bbase = bt * 32;

    float acc[4][4];                // [bj][cj]
    #pragma unroll
    for (int i = 0; i < 4; ++i)
        #pragma unroll
        for (int q = 0; q < 4; ++q) acc[i][q] = 0.f;

    for (int s = 0; s < 3; ++s) {
        const int dbase = j * 96 + s * 32;

        // stage fc_w chunk: [100][32] -> Wl[k][c]
        for (int idx = t; idx < NCLS * 32; idx += 256) {
            const int c = idx >> 5;
            const int k = idx & 31;
            Wl[k * 132 + c] = fcw[c * D + dbase + k];
        }
        // stage Z tile: 32b x 32k; 8 lane-groups stage 4 rows each (bl in [0,32))
        const float Av = A[dbase + kl];
        const float Bv = B[dbase + kl];
        #pragma unroll
        for (int i = 0; i < 4; ++i) {
            const int bl = tg + i * 8;                 // 0..31
            const float xv = x[(bbase + bl) * D + dbase + kl];
            float sv, cv;
            sincosf(xv, &sv, &cv);
            Zl[bl * 36 + kl] = part1 + cv * Av + sv * Bv;
        }
        __syncthreads();

        #pragma unroll
        for (int k = 0; k < 32; ++k) {
            const float4 wv = *(const float4*)&Wl[k * 132 + c0];
            float zb[4];
            #pragma unroll
            for (int bj = 0; bj < 4; ++bj) zb[bj] = Zl[(b0 + bj) * 36 + k];
            #pragma unroll
            for (int bj = 0; bj < 4; ++bj) {
                acc[bj][0] += zb[bj] * wv.x;
                acc[bj][1] += zb[bj] * wv.y;
                acc[bj][2] += zb[bj] * wv.z;
                acc[bj][3] += zb[bj] * wv.w;
            }
        }
        __syncthreads();
    }

    if (c0 < NCLS) {
        #pragma unroll
        for (int bj = 0; bj < 4; ++bj) {
            const int row = bbase + b0 + bj;
            #pragma unroll
            for (int q = 0; q < 4; ++q) {
                const int c = c0 + q;
                if (c < NCLS) {
                    float v = acc[bj][q];
                    if (j == 0) v += fcb[c];      // fold bias in exactly once
                    atomicAdd(&out[row * NCLS + c], v);
                }
            }
        }
    }
}

extern "C" void kernel_launch(void* const* d_in, const int* in_sizes, int n_in,
                              void* d_out, int out_size, void* d_ws, size_t ws_size,
                              hipStream_t stream) {
    const float* x   = (const float*)d_in[0];
    const float* a   = (const float*)d_in[1];
    const float* b   = (const float*)d_in[2];
    const float* w5  = (const float*)d_in[3];
    const float* n5  = (const float*)d_in[4];
    const float* fcw = (const float*)d_in[5];
    const float* fcb = (const float*)d_in[6];
    float* out = (float*)d_out;
    float* wsf = (float*)d_ws;

    // Scratch: only 2*D floats (24 KB) for the a/b column sums.
    hipMemsetAsync(d_ws, 0, 2 * D * sizeof(float), stream);
    // d_out is re-poisoned before every timed launch -> zero it here; K2
    // accumulates split-K partials into it atomically.
    hipMemsetAsync(d_out, 0, (size_t)out_size * sizeof(float), stream);

    colsum_kernel<<<dim3(96, 3), 256, 0, stream>>>(a, b, wsf);
    fused_gemm_kernel<<<dim3(16, 32), 256, 0, stream>>>(x, w5, n5, fcw, fcb,
                                                        wsf, out);
}

// Round 4
// 133.393 us; speedup vs baseline: 1.2855x; 1.2855x over previous
//
#include <hip/hip_runtime.h>
#include <math.h>

#define D 3072
#define BATCH 512
#define NCLS 100
#define NPAD 112
#define KS 16
#define KCHUNK (D / KS)   // 192

typedef __attribute__((ext_vector_type(8))) short bf16x8;
typedef __attribute__((ext_vector_type(4))) float f32x4;

// ws byte layout (fast path):
//   0        : A colsum   (3072 f32)  12288 B
//   12288    : B colsum   (3072 f32)  12288 B
//   24576    : Wb bf16    [112][3072] 688128 B
//   712704   : Zb bf16    [512][3072] 3145728 B
//   3858432  : partials   [KS][512][112] f32  3670016 B
//   total 7528448 B
#define WS_OFF_W   24576
#define WS_OFF_Z   712704
#define WS_OFF_P   3858432
#define WS_NEED    (WS_OFF_P + (size_t)KS * BATCH * NPAD * 4)

__device__ inline unsigned short f2bf(float f) {
    unsigned u = __float_as_uint(f);
    u += 0x7FFF + ((u >> 16) & 1);          // round-to-nearest-even
    return (unsigned short)(u >> 16);
}

// ---------------------------------------------------------------------------
// K1: column sums over first index:  A[d] = sum_i a[i*D+d], B[d] = sum_i b[..]
// Grid (96,3) x 256. float4 coalesced; 8 atomicAdds/thread (96 contenders).
// ---------------------------------------------------------------------------
__global__ __launch_bounds__(256) void colsum_kernel(const float* __restrict__ a,
                                                     const float* __restrict__ b,
                                                     float* __restrict__ ws) {
    const int col  = blockIdx.y * 1024 + threadIdx.x * 4;
    const int row0 = blockIdx.x * 32;

    float4 sa = make_float4(0.f, 0.f, 0.f, 0.f);
    float4 sb = make_float4(0.f, 0.f, 0.f, 0.f);
    #pragma unroll
    for (int r = 0; r < 32; ++r) {
        const int i = row0 + r;
        const float4 va = *(const float4*)(a + i * D + col);
        const float4 vb = *(const float4*)(b + i * D + col);
        sa.x += va.x; sa.y += va.y; sa.z += va.z; sa.w += va.w;
        sb.x += vb.x; sb.y += vb.y; sb.z += vb.z; sb.w += vb.w;
    }
    atomicAdd(&ws[col + 0], sa.x);
    atomicAdd(&ws[col + 1], sa.y);
    atomicAdd(&ws[col + 2], sa.z);
    atomicAdd(&ws[col + 3], sa.w);
    atomicAdd(&ws[D + col + 0], sb.x);
    atomicAdd(&ws[D + col + 1], sb.y);
    atomicAdd(&ws[D + col + 2], sb.z);
    atomicAdd(&ws[D + col + 3], sb.w);
}

// ---------------------------------------------------------------------------
// K2: fc_w fp32 [100][3072] -> bf16 [112][3072], rows 100..111 zero-padded.
// 336 blocks x 256, 4 elems/thread, coalesced.
// ---------------------------------------------------------------------------
__global__ __launch_bounds__(256) void convw_kernel(const float* __restrict__ fcw,
                                                    unsigned short* __restrict__ Wb) {
    const int idx = blockIdx.x * 256 + threadIdx.x;    // 0..86015
    const int c  = idx / (D / 4);
    const int d  = (idx % (D / 4)) * 4;
    ushort4 o;
    if (c < NCLS) {
        const float4 v = *(const float4*)(fcw + c * D + d);
        o.x = f2bf(v.x); o.y = f2bf(v.y); o.z = f2bf(v.z); o.w = f2bf(v.w);
    } else {
        o.x = o.y = o.z = o.w = 0;
    }
    *(ushort4*)(Wb + c * D + d) = o;
}

// ---------------------------------------------------------------------------
// K3: Z[b,d] = part1 + cos(x)*A[d] + sin(x)*B[d] -> bf16 [512][3072].
// 1536 blocks x 256, 4 elems/thread. __sincosf (HW v_sin/v_cos); error
// ~1e-4 rel, ~1e-2 absolute on Z -- far under the 5.92 output threshold.
// ---------------------------------------------------------------------------
__global__ __launch_bounds__(256) void zgen_kernel(const float* __restrict__ x,
                                                   const float* __restrict__ w5,
                                                   const float* __restrict__ n5,
                                                   const float* __restrict__ ws,
                                                   unsigned short* __restrict__ Zb) {
    const int idx = blockIdx.x * 256 + threadIdx.x;    // 0..393215
    const int b = idx / (D / 4);
    const int d = (idx % (D / 4)) * 4;

    float part1 = 0.f;
    #pragma unroll
    for (int i = 0; i < 4; ++i)
        part1 += w5[i + 1] * n5[i + 1] + w5[i] * n5[i];

    const float4 xv = *(const float4*)(x + b * D + d);
    const float4 Av = *(const float4*)(ws + d);
    const float4 Bv = *(const float4*)(ws + D + d);

    float sv, cv;
    ushort4 o;
    __sincosf(xv.x, &sv, &cv); o.x = f2bf(part1 + cv * Av.x + sv * Bv.x);
    __sincosf(xv.y, &sv, &cv); o.y = f2bf(part1 + cv * Av.y + sv * Bv.y);
    __sincosf(xv.z, &sv, &cv); o.z = f2bf(part1 + cv * Av.z + sv * Bv.z);
    __sincosf(xv.w, &sv, &cv); o.w = f2bf(part1 + cv * Av.w + sv * Bv.w);
    *(ushort4*)(Zb + b * D + d) = o;
}

// ---------------------------------------------------------------------------
// K4: MFMA GEMM  out_part = Zb [512][3072] x Wb^T [112][3072], split-K=16.
// Grid (8 m-blocks, KS) x 256 (4 waves). Wave w owns m-tile 16 rows; 7 n-frags
// of 16; KCHUNK=192 -> 6 k-steps of 32. Fragments loaded straight from global
// (Zb+Wb fit in L2). A/B frag: lane holds row (lane&15), k = (lane>>4)*8+j.
// C/D: col=lane&15 (n), row=(lane>>4)*4+reg (m)  [verified mapping, m89].
// ---------------------------------------------------------------------------
__global__ __launch_bounds__(256) void mfma_gemm_kernel(
        const unsigned short* __restrict__ Zb,
        const unsigned short* __restrict__ Wb,
        float* __restrict__ part) {       // [KS][512][112]
    const int wave = threadIdx.x >> 6;
    const int lane = threadIdx.x & 63;
    const int l16  = lane & 15;
    const int quad = lane >> 4;
    const int m0   = blockIdx.x * 64 + wave * 16;
    const int kbase = blockIdx.y * KCHUNK + quad * 8;

    f32x4 acc[7];
    #pragma unroll
    for (int n = 0; n < 7; ++n) acc[n] = (f32x4){0.f, 0.f, 0.f, 0.f};

    const unsigned short* za = Zb + (m0 + l16) * D + kbase;
    const unsigned short* wb = Wb + l16 * D + kbase;

    #pragma unroll
    for (int kk = 0; kk < KCHUNK; kk += 32) {
        const bf16x8 af = *(const bf16x8*)(za + kk);
        #pragma unroll
        for (int n = 0; n < 7; ++n) {
            const bf16x8 bf = *(const bf16x8*)(wb + n * 16 * D + kk);
            acc[n] = __builtin_amdgcn_mfma_f32_16x16x32_bf16(af, bf, acc[n], 0, 0, 0);
        }
    }

    float* pb = part + (size_t)blockIdx.y * (BATCH * NPAD);
    #pragma unroll
    for (int n = 0; n < 7; ++n)
        #pragma unroll
        for (int r = 0; r < 4; ++r)
            pb[(m0 + quad * 4 + r) * NPAD + n * 16 + l16] = acc[n][r];
}

// ---------------------------------------------------------------------------
// K5: out[b,c] = fcb[c] + sum_ks part[ks][b][c]   (c<100)
// ---------------------------------------------------------------------------
__global__ __launch_bounds__(256) void reduce2_kernel(const float* __restrict__ part,
                                                      const float* __restrict__ fcb,
                                                      float* __restrict__ out) {
    const int idx = blockIdx.x * 256 + threadIdx.x;
    if (idx >= BATCH * NCLS) return;
    const int b = idx / NCLS;
    const int c = idx % NCLS;
    float s = fcb[c];
    #pragma unroll
    for (int ks = 0; ks < KS; ++ks)
        s += part[ks * (BATCH * NPAD) + b * NPAD + c];
    out[idx] = s;
}

// ---------------------------------------------------------------------------
// Fallback (R3's verified path) if ws_size < WS_NEED: fused VALU GEMM with
// atomic split-K into d_out. Slow (57us) but correct and ws-light.
// ---------------------------------------------------------------------------
__global__ __launch_bounds__(256) void fused_gemm_kernel(
        const float* __restrict__ x,
        const float* __restrict__ w5,
        const float* __restrict__ n5,
        const float* __restrict__ fcw,
        const float* __restrict__ fcb,
        const float* __restrict__ ws,
        float* __restrict__ out) {
    __shared__ __align__(16) float Zl[32 * 36];
    __shared__ __align__(16) float Wl[32 * 132];

    const int t  = threadIdx.x;
    const int bt = blockIdx.x;
    const int j  = blockIdx.y;
    const float* __restrict__ A = ws;
    const float* __restrict__ B = ws + D;

    float part1 = 0.f;
    #pragma unroll
    for (int i = 0; i < 4; ++i)
        part1 += w5[i + 1] * n5[i + 1] + w5[i] * n5[i];

    const int c0 = (t & 31) * 4;
    const int b0 = (t >> 5) * 4;
    const int kl = t & 31;
    const int tg = t >> 5;
    const int bbase = bt * 32;

    float acc[4][4];
    #pragma unroll
    for (int i = 0; i < 4; ++i)
        #pragma unroll
        for (int q = 0; q < 4; ++q) acc[i][q] = 0.f;

    for (int s = 0; s < 3; ++s) {
        const int dbase = j * 96 + s * 32;
        for (int idx = t; idx < NCLS * 32; idx += 256) {
            const int c = idx >> 5;
            const int k = idx & 31;
            Wl[k * 132 + c] = fcw[c * D + dbase + k];
        }
        const float Av = A[dbase + kl];
        const float Bv = B[dbase + kl];
        #pragma unroll
        for (int i = 0; i < 4; ++i) {
            const int bl = tg + i * 8;
            const float xv = x[(bbase + bl) * D + dbase + kl];
            float sv, cv;
            sincosf(xv, &sv, &cv);
            Zl[bl * 36 + kl] = part1 + cv * Av + sv * Bv;
        }
        __syncthreads();
        #pragma unroll
        for (int k = 0; k < 32; ++k) {
            const float4 wv = *(const float4*)&Wl[k * 132 + c0];
            float zb[4];
            #pragma unroll
            for (int bj = 0; bj < 4; ++bj) zb[bj] = Zl[(b0 + bj) * 36 + k];
            #pragma unroll
            for (int bj = 0; bj < 4; ++bj) {
                acc[bj][0] += zb[bj] * wv.x;
                acc[bj][1] += zb[bj] * wv.y;
                acc[bj][2] += zb[bj] * wv.z;
                acc[bj][3] += zb[bj] * wv.w;
            }
        }
        __syncthreads();
    }

    if (c0 < NCLS) {
        #pragma unroll
        for (int bj = 0; bj < 4; ++bj) {
            const int row = bbase + b0 + bj;
            #pragma unroll
            for (int q = 0; q < 4; ++q) {
                const int c = c0 + q;
                if (c < NCLS) {
                    float v = acc[bj][q];
                    if (j == 0) v += fcb[c];
                    atomicAdd(&out[row * NCLS + c], v);
                }
            }
        }
    }
}

extern "C" void kernel_launch(void* const* d_in, const int* in_sizes, int n_in,
                              void* d_out, int out_size, void* d_ws, size_t ws_size,
                              hipStream_t stream) {
    const float* x   = (const float*)d_in[0];
    const float* a   = (const float*)d_in[1];
    const float* b   = (const float*)d_in[2];
    const float* w5  = (const float*)d_in[3];
    const float* n5  = (const float*)d_in[4];
    const float* fcw = (const float*)d_in[5];
    const float* fcb = (const float*)d_in[6];
    float* out = (float*)d_out;
    float* wsf = (float*)d_ws;

    hipMemsetAsync(d_ws, 0, 2 * D * sizeof(float), stream);
    colsum_kernel<<<dim3(96, 3), 256, 0, stream>>>(a, b, wsf);

    if (ws_size >= WS_NEED) {
        unsigned short* Wb = (unsigned short*)((char*)d_ws + WS_OFF_W);
        unsigned short* Zb = (unsigned short*)((char*)d_ws + WS_OFF_Z);
        float*          Pp = (float*)((char*)d_ws + WS_OFF_P);
        convw_kernel<<<dim3(336), 256, 0, stream>>>(fcw, Wb);
        zgen_kernel<<<dim3(1536), 256, 0, stream>>>(x, w5, n5, wsf, Zb);
        mfma_gemm_kernel<<<dim3(8, KS), 256, 0, stream>>>(Zb, Wb, Pp);
        reduce2_kernel<<<dim3(200), 256, 0, stream>>>(Pp, fcb, out);
    } else {
        hipMemsetAsync(d_out, 0, (size_t)out_size * sizeof(float), stream);
        fused_gemm_kernel<<<dim3(16, 32), 256, 0, stream>>>(x, w5, n5, fcw, fcb,
                                                            wsf, out);
    }
}

// Round 5
// 127.652 us; speedup vs baseline: 1.3434x; 1.0450x over previous
//
#include <hip/hip_runtime.h>
#include <math.h>

#define D 3072
#define BATCH 512
#define NCLS 100
#define NPAD 112
#define KS 32
#define KCHUNK (D / KS)   // 96

typedef __attribute__((ext_vector_type(8))) short bf16x8;
typedef __attribute__((ext_vector_type(4))) float f32x4;

// ws byte layout (fast path):
//   0       : A colsum (3072 f32) + B colsum (3072 f32)   24576 B
//   24576   : Wb bf16 [112][3072]                          688128 B
//   712704  : partials [KS][512][112] f32                  7340032 B
#define WS_OFF_W   24576
#define WS_OFF_P   712704
#define WS_NEED    (WS_OFF_P + (size_t)KS * BATCH * NPAD * 4)

__device__ inline unsigned short f2bf(float f) {
    unsigned u = __float_as_uint(f);
    u += 0x7FFF + ((u >> 16) & 1);          // round-to-nearest-even
    return (unsigned short)(u >> 16);
}

// ---------------------------------------------------------------------------
// K1 "prep": two independent jobs in one dispatch (saves a launch):
//  blocks [0,288):   colsum  A[d]=sum_i a[i*D+d], B[d]=sum_i b[i*D+d]
//                    (96 row-chunks x 3 col-groups, float4, atomics: 96/addr)
//  blocks [288,624): convert fc_w fp32 [100][3072] -> bf16 [112][3072],
//                    rows 100..111 zeroed (GEMM N-padding)
// ---------------------------------------------------------------------------
__global__ __launch_bounds__(256) void prep_kernel(const float* __restrict__ a,
                                                   const float* __restrict__ b,
                                                   const float* __restrict__ fcw,
                                                   float* __restrict__ ws,
                                                   unsigned short* __restrict__ Wb) {
    const int bid = blockIdx.x;
    const int t   = threadIdx.x;
    if (bid < 288) {
        const int rc   = bid / 3;
        const int cg   = bid % 3;
        const int col  = cg * 1024 + t * 4;
        const int row0 = rc * 32;
        float4 sa = make_float4(0.f, 0.f, 0.f, 0.f);
        float4 sb = make_float4(0.f, 0.f, 0.f, 0.f);
        #pragma unroll
        for (int r = 0; r < 32; ++r) {
            const int i = row0 + r;
            const float4 va = *(const float4*)(a + i * D + col);
            const float4 vb = *(const float4*)(b + i * D + col);
            sa.x += va.x; sa.y += va.y; sa.z += va.z; sa.w += va.w;
            sb.x += vb.x; sb.y += vb.y; sb.z += vb.z; sb.w += vb.w;
        }
        atomicAdd(&ws[col + 0], sa.x);
        atomicAdd(&ws[col + 1], sa.y);
        atomicAdd(&ws[col + 2], sa.z);
        atomicAdd(&ws[col + 3], sa.w);
        atomicAdd(&ws[D + col + 0], sb.x);
        atomicAdd(&ws[D + col + 1], sb.y);
        atomicAdd(&ws[D + col + 2], sb.z);
        atomicAdd(&ws[D + col + 3], sb.w);
    } else {
        const int idx = (bid - 288) * 256 + t;     // 0..86015
        const int c   = idx / (D / 4);
        const int d   = (idx % (D / 4)) * 4;
        ushort4 o;
        if (c < NCLS) {
            const float4 v = *(const float4*)(fcw + c * D + d);
            o.x = f2bf(v.x); o.y = f2bf(v.y); o.z = f2bf(v.z); o.w = f2bf(v.w);
        } else {
            o.x = o.y = o.z = o.w = 0;
        }
        *(ushort4*)(Wb + c * D + d) = o;
    }
}

// ---------------------------------------------------------------------------
// K2 "fzgemm": fused Z-gen + MFMA GEMM, split-K.
//   Z[b,d] = part1 + cos(x)*A[d] + sin(x)*B[d]  computed on the fly into the
//   A-fragment (each Z element feeds exactly ONE fragment -> zero redundancy),
//   then partial[j] = Z_chunk x Wb^T  via 16x16x32 bf16 MFMA.
// Grid (8 m-blocks, KS=32 k-chunks) x 256 = 256 blocks (1/CU).
// A/B frag: lane = row/col (lane&15), k = (lane>>4)*8 + j.
// C/D:      col = lane&15, row = (lane>>4)*4 + reg   [verified R4].
// ---------------------------------------------------------------------------
__global__ __launch_bounds__(256) void fzgemm_kernel(
        const float* __restrict__ x,
        const float* __restrict__ w5,
        const float* __restrict__ n5,
        const float* __restrict__ ws,               // A=ws[0:D], B=ws[D:2D]
        const unsigned short* __restrict__ Wb,      // [112][3072] bf16
        float* __restrict__ part) {                 // [KS][512][112]
    const int wave = threadIdx.x >> 6;
    const int lane = threadIdx.x & 63;
    const int l16  = lane & 15;
    const int quad = lane >> 4;
    const int m0   = blockIdx.x * 64 + wave * 16;   // m-tile base (16 rows)
    const int j    = blockIdx.y;                    // k-chunk
    const int kb   = j * KCHUNK + quad * 8;         // this lane's k base

    float part1 = 0.f;
    #pragma unroll
    for (int i = 0; i < 4; ++i)
        part1 += w5[i + 1] * n5[i + 1] + w5[i] * n5[i];

    f32x4 acc[7];
    #pragma unroll
    for (int n = 0; n < 7; ++n) acc[n] = (f32x4){0.f, 0.f, 0.f, 0.f};

    const float* xr = x + (m0 + l16) * D;           // this lane's x row

    #pragma unroll
    for (int kk = 0; kk < KCHUNK; kk += 32) {
        const int col = kb + kk;
        const float4 xv0 = *(const float4*)(xr + col);
        const float4 xv1 = *(const float4*)(xr + col + 4);
        const float4 Av0 = *(const float4*)(ws + col);
        const float4 Av1 = *(const float4*)(ws + col + 4);
        const float4 Bv0 = *(const float4*)(ws + D + col);
        const float4 Bv1 = *(const float4*)(ws + D + col + 4);

        union { bf16x8 v; unsigned short s[8]; } af;
        float sv, cv;
        __sincosf(xv0.x, &sv, &cv); af.s[0] = f2bf(part1 + cv * Av0.x + sv * Bv0.x);
        __sincosf(xv0.y, &sv, &cv); af.s[1] = f2bf(part1 + cv * Av0.y + sv * Bv0.y);
        __sincosf(xv0.z, &sv, &cv); af.s[2] = f2bf(part1 + cv * Av0.z + sv * Bv0.z);
        __sincosf(xv0.w, &sv, &cv); af.s[3] = f2bf(part1 + cv * Av0.w + sv * Bv0.w);
        __sincosf(xv1.x, &sv, &cv); af.s[4] = f2bf(part1 + cv * Av1.x + sv * Bv1.x);
        __sincosf(xv1.y, &sv, &cv); af.s[5] = f2bf(part1 + cv * Av1.y + sv * Bv1.y);
        __sincosf(xv1.z, &sv, &cv); af.s[6] = f2bf(part1 + cv * Av1.z + sv * Bv1.z);
        __sincosf(xv1.w, &sv, &cv); af.s[7] = f2bf(part1 + cv * Av1.w + sv * Bv1.w);

        #pragma unroll
        for (int n = 0; n < 7; ++n) {
            const bf16x8 bf = *(const bf16x8*)(Wb + (n * 16 + l16) * D + col);
            acc[n] = __builtin_amdgcn_mfma_f32_16x16x32_bf16(af.v, bf, acc[n], 0, 0, 0);
        }
    }

    float* pb = part + (size_t)j * (BATCH * NPAD);
    #pragma unroll
    for (int n = 0; n < 7; ++n)
        #pragma unroll
        for (int r = 0; r < 4; ++r)
            pb[(m0 + quad * 4 + r) * NPAD + n * 16 + l16] = acc[n][r];
}

// ---------------------------------------------------------------------------
// K3: out[b,c] = fcb[c] + sum_ks part[ks][b][c]
// ---------------------------------------------------------------------------
__global__ __launch_bounds__(256) void reduce2_kernel(const float* __restrict__ part,
                                                      const float* __restrict__ fcb,
                                                      float* __restrict__ out) {
    const int idx = blockIdx.x * 256 + threadIdx.x;
    if (idx >= BATCH * NCLS) return;
    const int b = idx / NCLS;
    const int c = idx % NCLS;
    float s = fcb[c];
    #pragma unroll
    for (int ks = 0; ks < KS; ++ks)
        s += part[ks * (BATCH * NPAD) + b * NPAD + c];
    out[idx] = s;
}

// ---------------------------------------------------------------------------
// Fallback (R3's verified path) if ws_size < WS_NEED (ws is 256 MiB in
// practice -- this path is insurance only).
// ---------------------------------------------------------------------------
__global__ __launch_bounds__(256) void fused_gemm_kernel(
        const float* __restrict__ x,
        const float* __restrict__ w5,
        const float* __restrict__ n5,
        const float* __restrict__ fcw,
        const float* __restrict__ fcb,
        const float* __restrict__ ws,
        float* __restrict__ out) {
    __shared__ __align__(16) float Zl[32 * 36];
    __shared__ __align__(16) float Wl[32 * 132];
    const int t  = threadIdx.x;
    const int bt = blockIdx.x;
    const int j  = blockIdx.y;
    float part1 = 0.f;
    #pragma unroll
    for (int i = 0; i < 4; ++i)
        part1 += w5[i + 1] * n5[i + 1] + w5[i] * n5[i];
    const int c0 = (t & 31) * 4;
    const int b0 = (t >> 5) * 4;
    const int kl = t & 31;
    const int tg = t >> 5;
    const int bbase = bt * 32;
    float acc[4][4];
    #pragma unroll
    for (int i = 0; i < 4; ++i)
        #pragma unroll
        for (int q = 0; q < 4; ++q) acc[i][q] = 0.f;
    for (int s = 0; s < 3; ++s) {
        const int dbase = j * 96 + s * 32;
        for (int idx = t; idx < NCLS * 32; idx += 256) {
            const int c = idx >> 5;
            const int k = idx & 31;
            Wl[k * 132 + c] = fcw[c * D + dbase + k];
        }
        const float Av = ws[dbase + kl];
        const float Bv = ws[D + dbase + kl];
        #pragma unroll
        for (int i = 0; i < 4; ++i) {
            const int bl = tg + i * 8;
            const float xv = x[(bbase + bl) * D + dbase + kl];
            float sv, cv;
            sincosf(xv, &sv, &cv);
            Zl[bl * 36 + kl] = part1 + cv * Av + sv * Bv;
        }
        __syncthreads();
        #pragma unroll
        for (int k = 0; k < 32; ++k) {
            const float4 wv = *(const float4*)&Wl[k * 132 + c0];
            float zb[4];
            #pragma unroll
            for (int bj = 0; bj < 4; ++bj) zb[bj] = Zl[(b0 + bj) * 36 + k];
            #pragma unroll
            for (int bj = 0; bj < 4; ++bj) {
                acc[bj][0] += zb[bj] * wv.x;
                acc[bj][1] += zb[bj] * wv.y;
                acc[bj][2] += zb[bj] * wv.z;
                acc[bj][3] += zb[bj] * wv.w;
            }
        }
        __syncthreads();
    }
    if (c0 < NCLS) {
        #pragma unroll
        for (int bj = 0; bj < 4; ++bj) {
            const int row = bbase + b0 + bj;
            #pragma unroll
            for (int q = 0; q < 4; ++q) {
                const int c = c0 + q;
                if (c < NCLS) {
                    float v = acc[bj][q];
                    if (j == 0) v += fcb[c];
                    atomicAdd(&out[row * NCLS + c], v);
                }
            }
        }
    }
}

extern "C" void kernel_launch(void* const* d_in, const int* in_sizes, int n_in,
                              void* d_out, int out_size, void* d_ws, size_t ws_size,
                              hipStream_t stream) {
    const float* x   = (const float*)d_in[0];
    const float* a   = (const float*)d_in[1];
    const float* b   = (const float*)d_in[2];
    const float* w5  = (const float*)d_in[3];
    const float* n5  = (const float*)d_in[4];
    const float* fcw = (const float*)d_in[5];
    const float* fcb = (const float*)d_in[6];
    float* out = (float*)d_out;
    float* wsf = (float*)d_ws;

    hipMemsetAsync(d_ws, 0, 2 * D * sizeof(float), stream);

    if (ws_size >= WS_NEED) {
        unsigned short* Wb = (unsigned short*)((char*)d_ws + WS_OFF_W);
        float*          Pp = (float*)((char*)d_ws + WS_OFF_P);
        prep_kernel<<<dim3(624), 256, 0, stream>>>(a, b, fcw, wsf, Wb);
        fzgemm_kernel<<<dim3(8, KS), 256, 0, stream>>>(x, w5, n5, wsf, Wb, Pp);
        reduce2_kernel<<<dim3(200), 256, 0, stream>>>(Pp, fcb, out);
    } else {
        hipMemsetAsync(d_out, 0, (size_t)out_size * sizeof(float), stream);
        prep_kernel<<<dim3(288), 256, 0, stream>>>(a, b, fcw, wsf,
                                                   (unsigned short*)out /*unused*/);
        fused_gemm_kernel<<<dim3(16, 32), 256, 0, stream>>>(x, w5, n5, fcw, fcb,
                                                            wsf, out);
    }
}